// Round 1
// baseline (1335.157 us; speedup 1.0000x reference)
//
#include <hip/hip_runtime.h>
#include <stdint.h>

#define DX 1024
#define NB 64
#define DY 10
#define NJK 100

typedef __attribute__((ext_vector_type(8))) short short8;
typedef __attribute__((ext_vector_type(4))) float f32x4;

__device__ __forceinline__ unsigned short f2bf(float f) {
  unsigned int u = __builtin_bit_cast(unsigned int, f);
  u += 0x7fffu + ((u >> 16) & 1u);
  return (unsigned short)(u >> 16);
}
__device__ __forceinline__ float bf2f(unsigned short h) {
  unsigned int u = ((unsigned int)h) << 16;
  return __builtin_bit_cast(float, u);
}

// ---------------------------------------------------------------------------
// K1: A[b] = X[b] @ X[b], split-bf16 3-pass MFMA (precision ~f32).
// Output: At_hi/At_lo bf16, layout [p][b][m]  (A[b,m,p] at ((p*64+b)*1024+m))
// 128x128 tile, BK=64, 4 waves (2x2), 4x4 16x16 frags per wave.
// ---------------------------------------------------------------------------
__launch_bounds__(256)
__global__ void k1_gemm(const float* __restrict__ X,
                        unsigned short* __restrict__ Ahg,
                        unsigned short* __restrict__ Alg) {
  __shared__ unsigned short Ah_s[128 * 64];
  __shared__ unsigned short Al_s[128 * 64];
  __shared__ unsigned short Bh_s[128 * 64];
  __shared__ unsigned short Bl_s[128 * 64];

  // XCD-chunked swizzle: XCD x runs original ids [x*512, (x+1)*512) -> one
  // XCD handles 8 whole batches; X[b] (4MB) stays resident in its L2.
  int wg = blockIdx.x;
  int swz = (wg & 7) * (gridDim.x >> 3) + (wg >> 3);
  int b = swz >> 6;
  int tile = swz & 63;
  int m0 = (tile >> 3) * 128;
  int p0 = (tile & 7) * 128;
  const float* Xb = X + (size_t)b * (DX * DX);

  int t = threadIdx.x;
  int wv = t >> 6, lane = t & 63, lr = lane & 15, lg = lane >> 4;
  int wm = (wv >> 1) * 64, wp = (wv & 1) * 64;

  f32x4 acc[4][4];
  for (int mi = 0; mi < 4; ++mi)
    for (int ni = 0; ni < 4; ++ni)
      for (int i = 0; i < 4; ++i) acc[mi][ni][i] = 0.f;

  int tr_ = t >> 4;  // 0..15
  int tc_ = t & 15;  // 0..15 (k chunk of 4)

  for (int kt = 0; kt < 16; ++kt) {
    int k0 = kt * 64;
    // ---- stage A tile: X[m0+m][k0+k], natural layout rows=m, cols=k ----
    for (int pass = 0; pass < 8; ++pass) {
      int m = tr_ + pass * 16;
      const float4 v = *(const float4*)(Xb + (size_t)(m0 + m) * DX + k0 + tc_ * 4);
      float vv[4] = {v.x, v.y, v.z, v.w};
      unsigned short h[4], l[4];
      for (int i = 0; i < 4; ++i) {
        h[i] = f2bf(vv[i]);
        l[i] = f2bf(vv[i] - bf2f(h[i]));
      }
      int idx = (m * 64 + tc_ * 4) ^ ((m & 7) << 3);  // XOR swizzle (16B slots)
      *(uint2*)&Ah_s[idx] = make_uint2(h[0] | ((unsigned)h[1] << 16), h[2] | ((unsigned)h[3] << 16));
      *(uint2*)&Al_s[idx] = make_uint2(l[0] | ((unsigned)l[1] << 16), l[2] | ((unsigned)l[3] << 16));
    }
    // ---- stage B tile transposed: Bt[p][k] = X[k0+k][p0+p], 4x4 reg blocks --
    for (int bi = 0; bi < 2; ++bi) {
      int blk = t + bi * 256;
      int kb = blk >> 5, pb = blk & 31;
      float rr[4][4];
      for (int r = 0; r < 4; ++r) {
        const float4 v = *(const float4*)(Xb + (size_t)(k0 + 4 * kb + r) * DX + p0 + 4 * pb);
        rr[r][0] = v.x; rr[r][1] = v.y; rr[r][2] = v.z; rr[r][3] = v.w;
      }
      for (int j = 0; j < 4; ++j) {
        unsigned short h[4], l[4];
        for (int r = 0; r < 4; ++r) {
          float x = rr[r][j];
          h[r] = f2bf(x);
          l[r] = f2bf(x - bf2f(h[r]));
        }
        int p_ = 4 * pb + j;
        int idx = (p_ * 64 + 4 * kb) ^ ((p_ & 7) << 3);
        *(uint2*)&Bh_s[idx] = make_uint2(h[0] | ((unsigned)h[1] << 16), h[2] | ((unsigned)h[3] << 16));
        *(uint2*)&Bl_s[idx] = make_uint2(l[0] | ((unsigned)l[1] << 16), l[2] | ((unsigned)l[3] << 16));
      }
    }
    __syncthreads();
    // ---- compute: 96 MFMAs per wave per K-step (3-pass split) ----
    for (int s = 0; s < 2; ++s) {
      int kk = s * 32 + lg * 8;
      short8 Afh[4], Afl[4], Bfh[4], Bfl[4];
      for (int mi = 0; mi < 4; ++mi) {
        int r = wm + 16 * mi + lr;
        int idx = (r * 64 + kk) ^ ((r & 7) << 3);
        Afh[mi] = *(const short8*)&Ah_s[idx];
        Afl[mi] = *(const short8*)&Al_s[idx];
      }
      for (int ni = 0; ni < 4; ++ni) {
        int r = wp + 16 * ni + lr;
        int idx = (r * 64 + kk) ^ ((r & 7) << 3);
        Bfh[ni] = *(const short8*)&Bh_s[idx];
        Bfl[ni] = *(const short8*)&Bl_s[idx];
      }
      for (int mi = 0; mi < 4; ++mi)
        for (int ni = 0; ni < 4; ++ni) {
          acc[mi][ni] = __builtin_amdgcn_mfma_f32_16x16x32_bf16(Afh[mi], Bfh[ni], acc[mi][ni], 0, 0, 0);
          acc[mi][ni] = __builtin_amdgcn_mfma_f32_16x16x32_bf16(Afh[mi], Bfl[ni], acc[mi][ni], 0, 0, 0);
          acc[mi][ni] = __builtin_amdgcn_mfma_f32_16x16x32_bf16(Afl[mi], Bfh[ni], acc[mi][ni], 0, 0, 0);
        }
    }
    __syncthreads();
  }
  // ---- epilogue: write A as hi/lo bf16 to At[p][b][m] ----
  for (int mi = 0; mi < 4; ++mi)
    for (int ni = 0; ni < 4; ++ni) {
      f32x4 a = acc[mi][ni];
      int m = m0 + wm + 16 * mi + lg * 4;  // C row = (lg*4+i)
      int p = p0 + wp + 16 * ni + lr;      // C col = lr
      size_t base = ((size_t)p * NB + b) * DX + m;
      unsigned short h[4], l[4];
      for (int i = 0; i < 4; ++i) {
        float x = a[i];
        h[i] = f2bf(x);
        l[i] = f2bf(x - bf2f(h[i]));
      }
      *(uint2*)(Ahg + base) = make_uint2(h[0] | ((unsigned)h[1] << 16), h[2] | ((unsigned)h[3] << 16));
      *(uint2*)(Alg + base) = make_uint2(l[0] | ((unsigned)l[1] << 16), l[2] | ((unsigned)l[3] << 16));
    }
}

// ---------------------------------------------------------------------------
// K2: one workgroup per p.  Numerator: bf16 MFMA  C[b,jk] += A[b,m]*R[m,jk]
// (M=64, N=112(pad of 100), K=1024 in 8 chunks of 128).
// Trace: f32 path  tr[b] += sum_m (Ahi+Alo)[b,m] * S_p[m],
//   S_p[m] = sum_j rho[p,j,m,j] accumulated in f32 during rho staging.
// Partials written to ws (deterministic reduce in K3).
// ---------------------------------------------------------------------------
__launch_bounds__(256)
__global__ void k2_contract(const float* __restrict__ rho,
                            const unsigned short* __restrict__ Ahg,
                            const unsigned short* __restrict__ Alg,
                            float* __restrict__ part_rho,
                            float* __restrict__ part_tr) {
  __shared__ unsigned short Ah_s[64 * 128];
  __shared__ unsigned short Al_s[64 * 128];
  __shared__ unsigned short R_s[112 * 128];  // rows = jk (100 used), cols = m
  __shared__ float S_s[128];
  __shared__ float red[256];

  int p = blockIdx.x;
  int t = threadIdx.x;
  int wv = t >> 6, lane = t & 63, lr = lane & 15, lg = lane >> 4;

  const float* rp = rho + (size_t)p * (DY * DX * DY);
  const unsigned short* Ahp = Ahg + (size_t)p * (NB * DX);
  const unsigned short* Alp = Alg + (size_t)p * (NB * DX);

  f32x4 acc[7];
  for (int n = 0; n < 7; ++n)
    for (int i = 0; i < 4; ++i) acc[n][i] = 0.f;
  float tracc = 0.f;

  for (int mc = 0; mc < 8; ++mc) {
    __syncthreads();  // previous chunk's LDS reads complete
    if (t < 128) S_s[t] = 0.f;
    __syncthreads();
    // stage rho chunk -> bf16 R_s + f32 diagonal sums S_s
    for (int u = t; u < 6400; u += 256) {
      int j = u / 640;
      int rem = u - j * 640;
      int m = rem / 5;
      int kp = (rem - m * 5) * 2;
      const float2 v = *(const float2*)(rp + (size_t)j * (DX * DY) + (size_t)(mc * 128 + m) * DY + kp);
      int row0 = j * DY + kp;
      R_s[(row0 * 128 + m) ^ ((row0 & 7) << 3)] = f2bf(v.x);
      int row1 = row0 + 1;
      R_s[(row1 * 128 + m) ^ ((row1 & 7) << 3)] = f2bf(v.y);
      if ((j & ~1) == kp) {  // k==j falls in this pair
        atomicAdd(&S_s[m], (j & 1) ? v.y : v.x);
      }
    }
    // stage A chunk (hi/lo bf16) into LDS
    {
      int b_ = t >> 2, q = t & 3;
      for (int q4 = 0; q4 < 4; ++q4) {
        int m8 = q * 32 + q4 * 8;
        uint4 hv = *(const uint4*)(Ahp + (size_t)b_ * DX + mc * 128 + m8);
        uint4 lv = *(const uint4*)(Alp + (size_t)b_ * DX + mc * 128 + m8);
        int idx = (b_ * 128 + m8) ^ ((b_ & 7) << 3);
        *(uint4*)&Ah_s[idx] = hv;
        *(uint4*)&Al_s[idx] = lv;
      }
    }
    __syncthreads();
    // f32 trace partial
    {
      int b_ = t >> 2, q = t & 3;
      float tsum = 0.f;
      for (int i = 0; i < 32; ++i) {
        int m = q * 32 + i;
        int idx = (b_ * 128 + m) ^ ((b_ & 7) << 3);
        tsum += (bf2f(Ah_s[idx]) + bf2f(Al_s[idx])) * S_s[m];
      }
      tracc += tsum;
    }
    // MFMA: wave wv owns C rows b = 16*wv..16*wv+15, all 7 N-tiles
    for (int s = 0; s < 4; ++s) {
      int kk = s * 32 + lg * 8;
      int ra = 16 * wv + lr;
      short8 af = *(const short8*)&Ah_s[(ra * 128 + kk) ^ ((ra & 7) << 3)];
      for (int n = 0; n < 7; ++n) {
        int rb = 16 * n + lr;
        short8 bf = *(const short8*)&R_s[(rb * 128 + kk) ^ ((rb & 7) << 3)];
        acc[n] = __builtin_amdgcn_mfma_f32_16x16x32_bf16(af, bf, acc[n], 0, 0, 0);
      }
    }
  }
  // epilogue: numerator partials
  for (int n = 0; n < 7; ++n) {
    int col = 16 * n + lr;
    if (col < NJK) {
      for (int i = 0; i < 4; ++i) {
        int b_ = 16 * wv + lg * 4 + i;
        part_rho[((size_t)p * NB + b_) * NJK + col] = acc[n][i];
      }
    }
  }
  // trace partials: thread t owns b_=t>>2, quarter q=t&3
  red[t] = tracc;
  __syncthreads();
  if (t < 64) {
    part_tr[p * NB + t] = red[4 * t] + red[4 * t + 1] + red[4 * t + 2] + red[4 * t + 3];
  }
}

// ---------------------------------------------------------------------------
// K3: reduce the 1024 per-p partials, divide by trace. One block per b.
// ---------------------------------------------------------------------------
__launch_bounds__(256)
__global__ void k3_reduce(const float* __restrict__ part_rho,
                          const float* __restrict__ part_tr,
                          float* __restrict__ out) {
  __shared__ float red[256];
  __shared__ float pr[2][128];
  int b = blockIdx.x;
  int t = threadIdx.x;
  float s = 0.f;
  for (int p = t; p < 1024; p += 256) s += part_tr[p * NB + b];
  red[t] = s;
  __syncthreads();
  for (int off = 128; off > 0; off >>= 1) {
    if (t < off) red[t] += red[t + off];
    __syncthreads();
  }
  float tr = red[0];
  int c = t & 127, half = t >> 7;
  float a = 0.f;
  if (c < NJK) {
    for (int p = half; p < 1024; p += 2)
      a += part_rho[((size_t)p * NB + b) * NJK + c];
  }
  pr[half][c] = a;
  __syncthreads();
  if (t < NJK) out[b * NJK + t] = (pr[0][t] + pr[1][t]) / tr;
}

extern "C" void kernel_launch(void* const* d_in, const int* in_sizes, int n_in,
                              void* d_out, int out_size, void* d_ws, size_t ws_size,
                              hipStream_t stream) {
  const float* X = (const float*)d_in[0];
  const float* rho = (const float*)d_in[1];
  float* out = (float*)d_out;
  char* ws = (char*)d_ws;

  const size_t SZ_A = (size_t)DX * NB * DX * sizeof(unsigned short);  // 128 MiB each
  const size_t SZ_PR = (size_t)DX * NB * NJK * sizeof(float);         // 25 MiB
  unsigned short* Ahg = (unsigned short*)(ws);
  unsigned short* Alg = (unsigned short*)(ws + SZ_A);
  float* part_rho = (float*)(ws + 2 * SZ_A);
  float* part_tr = (float*)(ws + 2 * SZ_A + SZ_PR);
  // total ws need: 2*128Mi + 25Mi + 256Ki  (~281.3 MiB)
  if (ws_size < 2 * SZ_A + SZ_PR + (size_t)DX * NB * sizeof(float)) return;

  hipLaunchKernelGGL(k1_gemm, dim3(4096), dim3(256), 0, stream, X, Ahg, Alg);
  hipLaunchKernelGGL(k2_contract, dim3(1024), dim3(256), 0, stream, rho, Ahg, Alg, part_rho, part_tr);
  hipLaunchKernelGGL(k3_reduce, dim3(NB), dim3(256), 0, stream, part_rho, part_tr, out);
}

// Round 2
// 905.537 us; speedup vs baseline: 1.4744x; 1.4744x over previous
//
#include <hip/hip_runtime.h>
#include <stdint.h>

#define DX 1024
#define NB 64
#define DY 10
#define NJK 100

typedef unsigned short ushort_t;
typedef __attribute__((ext_vector_type(8))) short short8;
typedef __attribute__((ext_vector_type(4))) float f32x4;
typedef __attribute__((ext_vector_type(16))) float f32x16;

__device__ __forceinline__ unsigned short f2bf(float f) {
  unsigned int u = __builtin_bit_cast(unsigned int, f);
  u += 0x7fffu + ((u >> 16) & 1u);
  return (unsigned short)(u >> 16);
}
__device__ __forceinline__ float bf2f(unsigned short h) {
  unsigned int u = ((unsigned int)h) << 16;
  return __builtin_bit_cast(float, u);
}
__device__ __forceinline__ void gload16(const void* g, void* l) {
  __builtin_amdgcn_global_load_lds((const __attribute__((address_space(1))) unsigned int*)g,
                                   (__attribute__((address_space(3))) unsigned int*)l, 16, 0, 0);
}

// ---------------------------------------------------------------------------
// P0a: Xt_h/Xt_l[b][p][k] = bf16 hi/lo split of X[b][k][p]  (transposed copy)
// 64x64 tiles through LDS; fully coalesced both sides.
// ---------------------------------------------------------------------------
__launch_bounds__(256)
__global__ void p0_transpose(const float* __restrict__ X,
                             ushort_t* __restrict__ Xth, ushort_t* __restrict__ Xtl) {
  __shared__ float T[64][65];
  int blk = blockIdx.x;
  int b = blk >> 8;
  int tt = blk & 255;
  int r0 = (tt >> 4) << 6;  // k rows of X
  int c0 = (tt & 15) << 6;  // p cols of X
  const float* Xb = X + (size_t)b * DX * DX;
  int t = threadIdx.x;
  int r = t >> 4, c = t & 15;
#pragma unroll
  for (int s = 0; s < 4; ++s) {
    const float4 v = *(const float4*)(Xb + (size_t)(r0 + r + 16 * s) * DX + c0 + c * 4);
    T[r + 16 * s][c * 4 + 0] = v.x;
    T[r + 16 * s][c * 4 + 1] = v.y;
    T[r + 16 * s][c * 4 + 2] = v.z;
    T[r + 16 * s][c * 4 + 3] = v.w;
  }
  __syncthreads();
#pragma unroll
  for (int s = 0; s < 4; ++s) {
    int pp = r + 16 * s;
    unsigned short h[4], l[4];
#pragma unroll
    for (int e = 0; e < 4; ++e) {
      float x = T[c * 4 + e][pp];
      h[e] = f2bf(x);
      l[e] = f2bf(x - bf2f(h[e]));
    }
    size_t base = ((size_t)b * DX + c0 + pp) * DX + r0 + c * 4;
    *(uint2*)(Xth + base) = make_uint2((unsigned)h[0] | ((unsigned)h[1] << 16),
                                       (unsigned)h[2] | ((unsigned)h[3] << 16));
    *(uint2*)(Xtl + base) = make_uint2((unsigned)l[0] | ((unsigned)l[1] << 16),
                                       (unsigned)l[2] | ((unsigned)l[3] << 16));
  }
}

// ---------------------------------------------------------------------------
// P0b: S[p][m] = sum_j rho[p][j][m][j]   (f32, 4 MiB)
// ---------------------------------------------------------------------------
__launch_bounds__(256)
__global__ void p0_sdiag(const float* __restrict__ rho, float* __restrict__ S) {
  int p = blockIdx.x;
  int t = threadIdx.x;
  const float* rp = rho + (size_t)p * (DY * DX * DY);
  float a0 = 0.f, a1 = 0.f, a2 = 0.f, a3 = 0.f;
#pragma unroll
  for (int j = 0; j < DY; ++j) {
    const float* base = rp + (size_t)j * (DX * DY) + j;
    a0 += base[(size_t)(4 * t + 0) * DY];
    a1 += base[(size_t)(4 * t + 1) * DY];
    a2 += base[(size_t)(4 * t + 2) * DY];
    a3 += base[(size_t)(4 * t + 3) * DY];
  }
  *(float4*)(S + (size_t)p * DX + 4 * t) = make_float4(a0, a1, a2, a3);
}

// ---------------------------------------------------------------------------
// K1: A[b] = X[b] @ X[b] via 3-pass split-bf16 MFMA (f32-accurate acc).
//  - 256x256 tile, BK=32, 512 thr (8 waves 2x4), 32x32x16 MFMA, dbuf LDS.
//  - B planes (hi/lo of X^T) via global_load_lds w/ source-side XOR swizzle.
//  - A planes reg-staged from f32 X, cvt, swizzled ds_write.
//  - epilogue: trace partial = <acc_f32, S[p,m]>  -> part_tr[b*16+tile];
//              Ah bf16 stored [p][b][m] via LDS transpose (coalesced).
// ---------------------------------------------------------------------------
#define K1_AH(buf) ((buf)*8192)
#define K1_AL(buf) (16384 + (buf)*8192)
#define K1_BH(buf) (32768 + (buf)*8192)
#define K1_BL(buf) (49152 + (buf)*8192)

__launch_bounds__(512, 2)
__global__ void k1_gemm(const float* __restrict__ X,
                        const ushort_t* __restrict__ Xth,
                        const ushort_t* __restrict__ Xtl,
                        const float* __restrict__ S,
                        ushort_t* __restrict__ Ahg,
                        float* __restrict__ part_tr) {
  __shared__ ushort_t lds[65536];  // 128 KiB
  int wg = blockIdx.x;
  int gt = (wg & 7) * 128 + (wg >> 3);  // XCD-chunked: one b per XCD at a time
  int b = gt >> 4;
  int tile = gt & 15;
  int m0 = (tile >> 2) << 8;
  int p0 = (tile & 3) << 8;
  int t = threadIdx.x;
  int wv = t >> 6, lane = t & 63, l31 = lane & 31, hi8 = lane >> 5;
  int wm = (wv >> 2) * 128, wp = (wv & 3) * 64;
  const float* Xb = X + (size_t)b * DX * DX;
  const size_t xtb = (size_t)b * DX * DX;

  f32x16 acc[4][2];
#pragma unroll
  for (int mi = 0; mi < 4; ++mi)
#pragma unroll
    for (int ni = 0; ni < 2; ++ni)
#pragma unroll
      for (int e = 0; e < 16; ++e) acc[mi][ni][e] = 0.f;

  int sm = t >> 1;   // A staging row (0..255)
  int skh = t & 1;   // k half (16 elements)
  float4 a0, a1, a2, a3;

  auto stageB = [&](int buf, int kt) {
#pragma unroll
    for (int i = 0; i < 2; ++i) {
      int c = i * 512 + t;
      int pr = c >> 2;
      int psl = c & 3;
      int lsl = psl ^ (pr & 3);
      size_t goff = xtb + (size_t)(p0 + pr) * DX + kt * 32 + lsl * 8;
      int wb = i * 512 + (t & ~63);
      gload16(Xth + goff, &lds[K1_BH(buf) + wb * 8]);
      gload16(Xtl + goff, &lds[K1_BL(buf) + wb * 8]);
    }
  };
  auto loadA = [&](int kt) {
    const float* src = Xb + (size_t)(m0 + sm) * DX + kt * 32 + skh * 16;
    a0 = *(const float4*)(src + 0);
    a1 = *(const float4*)(src + 4);
    a2 = *(const float4*)(src + 8);
    a3 = *(const float4*)(src + 12);
  };
  auto writeA = [&](int buf) {
    float v[16] = {a0.x, a0.y, a0.z, a0.w, a1.x, a1.y, a1.z, a1.w,
                   a2.x, a2.y, a2.z, a2.w, a3.x, a3.y, a3.z, a3.w};
    short8 ph[2], pl[2];
#pragma unroll
    for (int g = 0; g < 2; ++g)
#pragma unroll
      for (int e = 0; e < 8; ++e) {
        float x = v[g * 8 + e];
        unsigned short hh = f2bf(x);
        ph[g][e] = (short)hh;
        pl[g][e] = (short)f2bf(x - bf2f(hh));
      }
    int base = sm * 32;
    int s0 = (((skh * 2 + 0) ^ (sm & 3)) << 3);
    int s1 = (((skh * 2 + 1) ^ (sm & 3)) << 3);
    *(short8*)&lds[K1_AH(buf) + base + s0] = ph[0];
    *(short8*)&lds[K1_AH(buf) + base + s1] = ph[1];
    *(short8*)&lds[K1_AL(buf) + base + s0] = pl[0];
    *(short8*)&lds[K1_AL(buf) + base + s1] = pl[1];
  };
  auto compute = [&](int buf) {
#pragma unroll
    for (int ks = 0; ks < 2; ++ks) {
      short8 ah[4], al[4], bh[2], bl[2];
#pragma unroll
      for (int mi = 0; mi < 4; ++mi) {
        int m = wm + 32 * mi + l31;
        int idx = m * 32 + (((2 * ks + hi8) ^ (m & 3)) << 3);
        ah[mi] = *(const short8*)&lds[K1_AH(buf) + idx];
        al[mi] = *(const short8*)&lds[K1_AL(buf) + idx];
      }
#pragma unroll
      for (int ni = 0; ni < 2; ++ni) {
        int p = wp + 32 * ni + l31;
        int idx = p * 32 + (((2 * ks + hi8) ^ (p & 3)) << 3);
        bh[ni] = *(const short8*)&lds[K1_BH(buf) + idx];
        bl[ni] = *(const short8*)&lds[K1_BL(buf) + idx];
      }
#pragma unroll
      for (int mi = 0; mi < 4; ++mi)
#pragma unroll
        for (int ni = 0; ni < 2; ++ni) {
          acc[mi][ni] = __builtin_amdgcn_mfma_f32_32x32x16_bf16(ah[mi], bh[ni], acc[mi][ni], 0, 0, 0);
          acc[mi][ni] = __builtin_amdgcn_mfma_f32_32x32x16_bf16(ah[mi], bl[ni], acc[mi][ni], 0, 0, 0);
          acc[mi][ni] = __builtin_amdgcn_mfma_f32_32x32x16_bf16(al[mi], bh[ni], acc[mi][ni], 0, 0, 0);
        }
    }
  };

  // prologue
  stageB(0, 0);
  loadA(0);
  writeA(0);
  __syncthreads();
#pragma unroll 1
  for (int kt2 = 0; kt2 < 16; ++kt2) {
    int kt = kt2 * 2;
    stageB(1, kt + 1);
    loadA(kt + 1);
    compute(0);
    writeA(1);
    __syncthreads();
    if (kt2 < 15) {
      stageB(0, kt + 2);
      loadA(kt + 2);
    }
    compute(1);
    if (kt2 < 15) writeA(0);
    __syncthreads();
  }

  // ---- epilogue 1: trace partial from exact f32 accumulator ----
  float tracc = 0.f;
#pragma unroll
  for (int mi = 0; mi < 4; ++mi)
#pragma unroll
    for (int ni = 0; ni < 2; ++ni) {
      int p = p0 + wp + 32 * ni + l31;
#pragma unroll
      for (int rg = 0; rg < 4; ++rg) {
        int m = m0 + wm + 32 * mi + 8 * rg + 4 * hi8;
        const float4 sv = *(const float4*)(S + (size_t)p * DX + m);
        tracc += acc[mi][ni][rg * 4 + 0] * sv.x + acc[mi][ni][rg * 4 + 1] * sv.y +
                 acc[mi][ni][rg * 4 + 2] * sv.z + acc[mi][ni][rg * 4 + 3] * sv.w;
      }
    }
#pragma unroll
  for (int off = 32; off > 0; off >>= 1) tracc += __shfl_xor(tracc, off, 64);
  __syncthreads();
  if (lane == 0) ((float*)lds)[wv] = tracc;
  __syncthreads();
  if (t == 0) {
    float s = 0.f;
    for (int i = 0; i < 8; ++i) s += ((float*)lds)[i];
    part_tr[gt] = s;
  }
  __syncthreads();

  // ---- epilogue 2: Ah -> LDS [p][m] (swizzled) -> coalesced stores ----
#pragma unroll
  for (int mi = 0; mi < 4; ++mi)
#pragma unroll
    for (int ni = 0; ni < 2; ++ni) {
      int p = wp + 32 * ni + l31;
#pragma unroll
      for (int rg = 0; rg < 4; ++rg) {
        int m = wm + 32 * mi + 8 * rg + 4 * hi8;
        unsigned int h0 = f2bf(acc[mi][ni][rg * 4 + 0]);
        unsigned int h1 = f2bf(acc[mi][ni][rg * 4 + 1]);
        unsigned int h2 = f2bf(acc[mi][ni][rg * 4 + 2]);
        unsigned int h3 = f2bf(acc[mi][ni][rg * 4 + 3]);
        int idx = p * 256 + (((m >> 3) ^ (p & 7)) << 3) + (m & 7);
        *(uint2*)&lds[idx] = make_uint2(h0 | (h1 << 16), h2 | (h3 << 16));
      }
    }
  __syncthreads();
#pragma unroll
  for (int i = 0; i < 16; ++i) {
    int cc = i * 512 + t;
    int row = cc >> 5, sl = cc & 31;
    int idx = row * 256 + ((sl ^ (row & 7)) << 3);
    uint4 v = *(const uint4*)&lds[idx];
    *(uint4*)(Ahg + ((size_t)(p0 + row) * NB + b) * DX + m0 + sl * 8) = v;
  }
}

// ---------------------------------------------------------------------------
// K2: numerator only. One block per p: C[b,jk] += Ah[b,m]*R[m,jk], K=1024.
// ---------------------------------------------------------------------------
__launch_bounds__(256)
__global__ void k2_contract(const float* __restrict__ rho,
                            const ushort_t* __restrict__ Ahg,
                            float* __restrict__ part_rho) {
  __shared__ ushort_t Ah_s[8192];       // 64 b x 128 m (swizzled 16B slots)
  __shared__ ushort_t R_s[112 * 128];   // rows jk (100 used), cols m
  int p = blockIdx.x;
  int t = threadIdx.x;
  int wv = t >> 6, lane = t & 63, lr = lane & 15, lg = lane >> 4;
  const float* rp = rho + (size_t)p * (DY * DX * DY);
  const ushort_t* Ahp = Ahg + (size_t)p * (NB * DX);

  f32x4 acc[7];
#pragma unroll
  for (int n = 0; n < 7; ++n)
#pragma unroll
    for (int i = 0; i < 4; ++i) acc[n][i] = 0.f;

  for (int mc = 0; mc < 8; ++mc) {
    __syncthreads();
    // A tile via global_load_lds (source-side swizzle)
#pragma unroll
    for (int i = 0; i < 4; ++i) {
      int c = i * 256 + t;
      int br = c >> 4, psl = c & 15;
      int lsl = psl ^ (br & 7);
      const ushort_t* g = Ahp + (size_t)br * DX + mc * 128 + lsl * 8;
      int wb = i * 256 + (t & ~63);
      gload16(g, &Ah_s[wb * 8]);
    }
    // rho chunk -> bf16 R_s (transpose), coalesced float2 reads
    for (int u = t; u < 6400; u += 256) {
      int j = u / 640;
      int rem = u - j * 640;
      int m = rem / 5;
      int kp = (rem - m * 5) * 2;
      const float2 v = *(const float2*)(rp + (size_t)j * (DX * DY) + (size_t)(mc * 128 + m) * DY + kp);
      int row0 = j * DY + kp;
      R_s[(row0 * 128 + m) ^ ((row0 & 7) << 3)] = f2bf(v.x);
      int row1 = row0 + 1;
      R_s[(row1 * 128 + m) ^ ((row1 & 7) << 3)] = f2bf(v.y);
    }
    __syncthreads();
#pragma unroll
    for (int s = 0; s < 4; ++s) {
      int kk = s * 32 + lg * 8;
      int ra = 16 * wv + lr;
      short8 af = *(const short8*)&Ah_s[(ra * 128 + kk) ^ ((ra & 7) << 3)];
#pragma unroll
      for (int n = 0; n < 7; ++n) {
        int rb = 16 * n + lr;
        short8 bf = *(const short8*)&R_s[(rb * 128 + kk) ^ ((rb & 7) << 3)];
        acc[n] = __builtin_amdgcn_mfma_f32_16x16x32_bf16(af, bf, acc[n], 0, 0, 0);
      }
    }
  }
#pragma unroll
  for (int n = 0; n < 7; ++n) {
    int col = 16 * n + lr;
    if (col < NJK) {
#pragma unroll
      for (int i = 0; i < 4; ++i) {
        int b_ = 16 * wv + lg * 4 + i;
        part_rho[((size_t)p * NB + b_) * NJK + col] = acc[n][i];
      }
    }
  }
}

// ---------------------------------------------------------------------------
// K3a: partial p-reduction of numerator; K3b: finish + divide by trace.
// ---------------------------------------------------------------------------
__launch_bounds__(128)
__global__ void k3a(const float* __restrict__ part_rho, float* __restrict__ ws2) {
  int blk = blockIdx.x;  // 128 = 64 b x 2 halves
  int b = blk >> 1, h = blk & 1;
  int t = threadIdx.x;
  if (t >= NJK) return;
  float s = 0.f;
  for (int pp = 0; pp < 512; ++pp)
    s += part_rho[((size_t)(h * 512 + pp) * NB + b) * NJK + t];
  ws2[(size_t)(h * NB + b) * 128 + t] = s;
}

__launch_bounds__(128)
__global__ void k3b(const float* __restrict__ ws2, const float* __restrict__ part_tr,
                    float* __restrict__ out) {
  int b = blockIdx.x;
  int t = threadIdx.x;
  float tr = 0.f;
#pragma unroll
  for (int i = 0; i < 16; ++i) tr += part_tr[b * 16 + i];
  if (t < NJK) {
    float v = ws2[(size_t)b * 128 + t] + ws2[(size_t)(NB + b) * 128 + t];
    out[b * NJK + t] = v / tr;
  }
}

extern "C" void kernel_launch(void* const* d_in, const int* in_sizes, int n_in,
                              void* d_out, int out_size, void* d_ws, size_t ws_size,
                              hipStream_t stream) {
  const float* X = (const float*)d_in[0];
  const float* rho = (const float*)d_in[1];
  float* out = (float*)d_out;
  char* ws = (char*)d_ws;

  const size_t MB128 = 134217728ull;
  ushort_t* Xth = (ushort_t*)(ws);
  ushort_t* Xtl = (ushort_t*)(ws + MB128);
  ushort_t* Ahg = (ushort_t*)(ws + 2 * MB128);
  float* S = (float*)(ws + 3 * MB128);
  float* part_tr = (float*)(ws + 3 * MB128 + (4ull << 20));
  float* part_rho = (float*)(ws);        // overlays Xth (dead after K1)
  float* ws2 = (float*)(ws + MB128);     // overlays Xtl (dead after K1)
  size_t need = 3 * MB128 + (4ull << 20) + 65536;
  if (ws_size < need) return;

  hipLaunchKernelGGL(p0_transpose, dim3(16384), dim3(256), 0, stream, X, Xth, Xtl);
  hipLaunchKernelGGL(p0_sdiag, dim3(1024), dim3(256), 0, stream, rho, S);
  hipLaunchKernelGGL(k1_gemm, dim3(1024), dim3(512), 0, stream, X, Xth, Xtl, S, Ahg, part_tr);
  hipLaunchKernelGGL(k2_contract, dim3(1024), dim3(256), 0, stream, rho, Ahg, part_rho);
  hipLaunchKernelGGL(k3a, dim3(128), dim3(128), 0, stream, part_rho, ws2);
  hipLaunchKernelGGL(k3b, dim3(64), dim3(128), 0, stream, ws2, part_tr, out);
}